// Round 6
// baseline (6336.142 us; speedup 1.0000x reference)
//
#include <hip/hip_runtime.h>
#include <hip/hip_bf16.h>

// LSTM T=512 B=32 IN=H=1024 L=2. fp32 in/out, bf16 MFMA internally.
// Round 6: XCD-localized recurrence, deterministic occupancy (1 block/CU via
// 104KB LDS). l0 rec on XCD0 (h@W_hh only, K=1024, h via L2/sc0), l1 rec on
// XCD1, XG workers on XCDs 2-7 feed x-part gate rings through L3.
// All flags = proven agent atomics (no acquire -> no buffer_inv, no RMW polls).

namespace {
constexpr int T_STEPS = 512;
constexpr int HID     = 1024;
constexpr int G4H     = 4096;
constexpr int BH      = 32 * HID;                    // 32768
constexpr size_t MEM_ELEMS = (size_t)T_STEPS * BH;   // 16,777,216

// ---- mesh workspace layout (bytes) ----
constexpr size_t OFF_WFHH = 0;                        // bf16 frags [2][32r][8w][32f][64][8]
constexpr size_t SZ_WF1   = (size_t)32 * 8 * 32 * 64 * 8 * 2;   // 8,388,608
constexpr size_t OFF_WFI0 = OFF_WFHH + 2 * SZ_WF1;
constexpr size_t OFF_WFI1 = OFF_WFI0 + SZ_WF1;
constexpr size_t OFF_BIAS = OFF_WFI1 + SZ_WF1;        // f32 [2][4096]
constexpr size_t OFF_H0L  = OFF_BIAS + 32768;         // bf16 ring [8][32][1024]
constexpr size_t OFF_H1L  = OFF_H0L + (size_t)8 * BH * 2;
constexpr size_t OFF_H0X  = OFF_H1L + (size_t)8 * BH * 2;              // bf16 [513][32][1024]
constexpr size_t OFF_XG0  = OFF_H0X + (size_t)(T_STEPS + 1) * BH * 2;  // f32 [64][32r][32m][128]
constexpr size_t OFF_XG1  = OFF_XG0 + (size_t)64 * 32 * 32 * 128 * 4;  // f32 [16][32r][32m][128]
constexpr size_t OFF_CTRL = OFF_XG1 + (size_t)16 * 32 * 32 * 128 * 4;
constexpr size_t WS_MESH  = OFF_CTRL + 65536;         // ~110.3 MB

// ctrl u32 word offsets (spread across cachelines)
constexpr int CW_XCD  = 0;      // + xcd*16 : claim counters
constexpr int CW_CNT0 = 128;    // + r      : XG0 tickets
constexpr int CW_CNT1 = 192;    // + r      : XG1 tickets
constexpr int CW_L0P  = 256;    // l0 progress
constexpr int CW_L1P  = 272;    // l1 progress
constexpr int CW_IF0  = 512;    // + r*16   : intra flags L0
constexpr int CW_IF1  = 1024;   // + r*16   : intra flags L1
constexpr int CW_H0XF = 1536;   // + r*16   : h0 cross-XCD flags
constexpr int CW_XF0  = 2048;   // + slot*32 + r : xgate flags L0 (64 slots)
constexpr int CW_XF1  = 4096;   // + slot*32 + r : xgate flags L1 (16 slots)

// ---- tier-2 layout (round-1 proven) ----
constexpr size_t T2_W    = 0;
constexpr size_t T2_SZW  = (size_t)2 * G4H * 2048 * 2;
constexpr size_t T2_BIAS = T2_W + T2_SZW;
constexpr size_t T2_H0   = T2_BIAS + 32768;
constexpr size_t T2_H1   = T2_H0 + (size_t)2 * BH * 2;
constexpr size_t WS_STEP = T2_H1 + (size_t)2 * BH * 2;
}

typedef __attribute__((ext_vector_type(8))) short short8;
typedef __attribute__((ext_vector_type(4))) float f32x4;
typedef unsigned short u16;
typedef unsigned long long u64;

__device__ inline unsigned short f2bf(float x) {
  unsigned u = __builtin_bit_cast(unsigned, x);
  u += 0x7fffu + ((u >> 16) & 1u);          // RNE
  return (unsigned short)(u >> 16);
}
__device__ inline float sigm(float x) { return 1.0f / (1.0f + __expf(-x)); }

// coherent agent-scope (L2-bypass) 16B load as 2x u64 atomic loads (proven r4)
__device__ inline short8 ld_sc16(const u16* p) {
  const u64* q = (const u64*)p;
  u64 q0 = __hip_atomic_load(q,     __ATOMIC_RELAXED, __HIP_MEMORY_SCOPE_AGENT);
  u64 q1 = __hip_atomic_load(q + 1, __ATOMIC_RELAXED, __HIP_MEMORY_SCOPE_AGENT);
  union { u64 u[2]; short8 s; } r; r.u[0] = q0; r.u[1] = q1; return r.s;
}
// L2-scope (sc0) helpers: store is write-through to L2; load bypasses L1.
__device__ inline void st_u16_sc0(u16* p, unsigned v) {
  asm volatile("global_store_short %0, %1, off sc0" :: "v"(p), "v"(v) : "memory");
}

// ---------------- cvt: weight fragments + bias + initial h ----------------
__global__ void cvt_mesh(const float* __restrict__ Wih, const float* __restrict__ Whh,
                         const float* __restrict__ bih, const float* __restrict__ bhh,
                         const float* __restrict__ h0,
                         u16* __restrict__ WFHH, u16* __restrict__ WFI0, u16* __restrict__ WFI1,
                         float* __restrict__ bias, u16* __restrict__ H0L, u16* __restrict__ H1L) {
  size_t idx = (size_t)blockIdx.x * blockDim.x + threadIdx.x;
  size_t stride = (size_t)gridDim.x * blockDim.x;
  const size_t NFRAG = (size_t)4 * 524288;   // 4 arrays x 2^19 frags
  for (size_t fi = idx; fi < NFRAG; fi += stride) {
    int arr = (int)(fi >> 19);
    unsigned i = (unsigned)(fi & 524287u);
    int lane = i & 63, f = (i >> 6) & 31, w = (i >> 11) & 7, r = i >> 14;
    int nt = f >> 3, kc = f & 7, nhh = w & 1, kss = w >> 1;
    int l15 = lane & 15, lqq = lane >> 4;
    int nl = nhh * 64 + nt * 16 + l15;        // col within the 128-gate block
    int g = nl >> 5, uu = nl & 31;            // gate (i,f,g,o), unit-in-role
    int grow = g * 1024 + r * 32 + uu;        // global weight row
    int kb = kss * 256 + kc * 32 + lqq * 8;   // K offset
    const float* src = (arr == 0) ? Whh + (size_t)grow * 1024 + kb
                     : (arr == 1) ? Whh + (size_t)(4096 + grow) * 1024 + kb
                     : (arr == 2) ? Wih + (size_t)grow * 1024 + kb
                                  : Wih + (size_t)(4096 + grow) * 1024 + kb;
    u16* dst = ((arr == 0) ? WFHH : (arr == 1) ? (WFHH + 4194304) : (arr == 2) ? WFI0 : WFI1)
               + (size_t)i * 8;
    short8 o;
    #pragma unroll
    for (int e = 0; e < 8; ++e) o[e] = (short)f2bf(src[e]);
    *(short8*)dst = o;
  }
  for (size_t i = idx; i < 8192; i += stride) bias[i] = bih[i] + bhh[i];
  for (size_t i = idx; i < (size_t)BH; i += stride) {
    H0L[i] = f2bf(h0[i]);
    H1L[i] = f2bf(h0[BH + i]);
  }
}

// ---------------- persistent mesh kernel ----------------
__global__ __launch_bounds__(512, 2) void lstm_mesh(
    const float* __restrict__ X, const float* __restrict__ c0in,
    float* __restrict__ out,
    const u16* __restrict__ WFHH, const u16* __restrict__ WFI0, const u16* __restrict__ WFI1,
    const float* __restrict__ bias,
    u16* __restrict__ H0L, u16* __restrict__ H1L, u16* __restrict__ H0X,
    float* __restrict__ XG0, float* __restrict__ XG1,
    unsigned* __restrict__ ctrl)
{
  // 104 KiB static LDS -> exactly 1 block/CU -> 32 blocks per XCD, guaranteed.
  __shared__ float redf[13][2][4][256];
  const int tid = threadIdx.x;

  // ---- deterministic role claim via XCC_ID ----
  if (tid == 0) {
    unsigned xcd;
    asm volatile("s_getreg_b32 %0, hwreg(HW_REG_XCC_ID)" : "=s"(xcd));
    xcd &= 7u;
    unsigned rk = __hip_atomic_fetch_add(&ctrl[CW_XCD + xcd * 16], 1u,
                                         __ATOMIC_RELAXED, __HIP_MEMORY_SCOPE_AGENT);
    unsigned kind, role;
    if (xcd == 0u)      { kind = (rk < 32u) ? 0u : 4u; role = rk & 31u; }
    else if (xcd == 1u) { kind = (rk < 32u) ? 1u : 4u; role = rk & 31u; }
    else if (xcd <= 4u) { kind = 2u; role = rk & 31u; }
    else                { kind = 3u; role = rk & 31u; }
    redf[0][0][0][0] = __builtin_bit_cast(float, kind);
    redf[0][0][0][1] = __builtin_bit_cast(float, role);
  }
  __syncthreads();
  const unsigned kind = __builtin_bit_cast(unsigned, redf[0][0][0][0]);
  const int r = (int)__builtin_bit_cast(unsigned, redf[0][0][0][1]);
  __syncthreads();
  if (kind == 4u) return;

  const int lane = tid & 63, wid = tid >> 6;
  const int l15 = lane & 15, lq = lane >> 4;
  const int ks = wid >> 1;                // K-slice 0..3 (256 each)
  const int u = tid & 31, m2 = tid >> 5;  // epilogue cell (m2,u) and (m2+16,u)
  const int col = r * 32 + u;
  const int lane16 = ((m2 >> 2) << 4) | (u & 15);
  const int reg = m2 & 3;

  // ---- weights into VGPRs (32 x short8 = 128 VGPR/lane), K=1024 per role ----
  const u16* wsrc =
      (kind == 0u) ? WFHH + ((size_t)(0 * 32 + r) * 8 + wid) * 16384
    : (kind == 1u) ? WFHH + ((size_t)(1 * 32 + r) * 8 + wid) * 16384
    : (kind == 2u) ? WFI0 + ((size_t)r * 8 + wid) * 16384
                   : WFI1 + ((size_t)r * 8 + wid) * 16384;
  short8 wb[32];
  #pragma unroll
  for (int f = 0; f < 32; ++f)
    wb[f] = *(const short8*)(wsrc + ((size_t)f * 64 + lane) * 8);

  float bs[4];
  if (kind >= 2u) {
    #pragma unroll
    for (int g = 0; g < 4; ++g)
      bs[g] = bias[(kind == 3u ? 4096 : 0) + g * 1024 + col];
  }

#define MFMA_ALL(AARR)                                                        \
  _Pragma("unroll")                                                           \
  for (int kc = 0; kc < 8; ++kc) {                                            \
    _Pragma("unroll")                                                         \
    for (int nt = 0; nt < 4; ++nt) {                                          \
      acc0[nt] = __builtin_amdgcn_mfma_f32_16x16x32_bf16(AARR[kc], wb[nt*8+kc], acc0[nt], 0, 0, 0); \
      acc1[nt] = __builtin_amdgcn_mfma_f32_16x16x32_bf16(AARR[8+kc], wb[nt*8+kc], acc1[nt], 0, 0, 0); \
    }                                                                         \
  }

#define RED_WRITE()                                                           \
  _Pragma("unroll")                                                           \
  for (int nt = 0; nt < 4; ++nt) {                                            \
    *(f32x4*)&redf[wid][0][nt][lane * 4] = acc0[nt];                          \
    *(f32x4*)&redf[wid][1][nt][lane * 4] = acc1[nt];                          \
  }                                                                           \
  __syncthreads();

#define RED_READ(GS)                                                          \
  _Pragma("unroll")                                                           \
  for (int mt = 0; mt < 2; ++mt) {                                            \
    _Pragma("unroll")                                                         \
    for (int g = 0; g < 4; ++g) {                                             \
      const int nhh = g >> 1;                                                 \
      const int ntl = (g * 2 + (u >> 4)) & 3;                                 \
      float v = 0.f;                                                          \
      _Pragma("unroll")                                                       \
      for (int kq = 0; kq < 4; ++kq)                                          \
        v += redf[kq * 2 + nhh][mt][ntl][lane16 * 4 + reg];                   \
      GS[mt][g] = v;                                                          \
    }                                                                         \
  }

#define LOAD16_SC0(HB0, HB1)                                                  \
  asm volatile(                                                               \
    "global_load_dwordx4 %0,  %16, off sc0\n\t"                               \
    "global_load_dwordx4 %1,  %16, off offset:64 sc0\n\t"                     \
    "global_load_dwordx4 %2,  %16, off offset:128 sc0\n\t"                    \
    "global_load_dwordx4 %3,  %16, off offset:192 sc0\n\t"                    \
    "global_load_dwordx4 %4,  %16, off offset:256 sc0\n\t"                    \
    "global_load_dwordx4 %5,  %16, off offset:320 sc0\n\t"                    \
    "global_load_dwordx4 %6,  %16, off offset:384 sc0\n\t"                    \
    "global_load_dwordx4 %7,  %16, off offset:448 sc0\n\t"                    \
    "global_load_dwordx4 %8,  %17, off sc0\n\t"                               \
    "global_load_dwordx4 %9,  %17, off offset:64 sc0\n\t"                     \
    "global_load_dwordx4 %10, %17, off offset:128 sc0\n\t"                    \
    "global_load_dwordx4 %11, %17, off offset:192 sc0\n\t"                    \
    "global_load_dwordx4 %12, %17, off offset:256 sc0\n\t"                    \
    "global_load_dwordx4 %13, %17, off offset:320 sc0\n\t"                    \
    "global_load_dwordx4 %14, %17, off offset:384 sc0\n\t"                    \
    "global_load_dwordx4 %15, %17, off offset:448 sc0\n\t"                    \
    "s_waitcnt vmcnt(0)"                                                      \
    : "=&v"(A0),"=&v"(A1),"=&v"(A2),"=&v"(A3),"=&v"(A4),"=&v"(A5),"=&v"(A6), \
      "=&v"(A7),"=&v"(A8),"=&v"(A9),"=&v"(A10),"=&v"(A11),"=&v"(A12),         \
      "=&v"(A13),"=&v"(A14),"=&v"(A15)                                        \
    : "v"(HB0), "v"(HB1)                                                      \
    : "memory");

#define AS_FROM_A()                                                           \
  short8 AS[16] = {                                                           \
    __builtin_bit_cast(short8,A0), __builtin_bit_cast(short8,A1),             \
    __builtin_bit_cast(short8,A2), __builtin_bit_cast(short8,A3),             \
    __builtin_bit_cast(short8,A4), __builtin_bit_cast(short8,A5),             \
    __builtin_bit_cast(short8,A6), __builtin_bit_cast(short8,A7),             \
    __builtin_bit_cast(short8,A8), __builtin_bit_cast(short8,A9),             \
    __builtin_bit_cast(short8,A10),__builtin_bit_cast(short8,A11),            \
    __builtin_bit_cast(short8,A12),__builtin_bit_cast(short8,A13),            \
    __builtin_bit_cast(short8,A14),__builtin_bit_cast(short8,A15) };

  // ================= recurrence blocks (XCD0 = l0, XCD1 = l1) =================
  if (kind <= 1u) {
    const int l = (int)kind;
    unsigned* intraF = ctrl + (l == 0 ? CW_IF0 : CW_IF1);
    unsigned* xflag  = ctrl + (l == 0 ? CW_XF0 : CW_XF1);
    const int xmask  = (l == 0) ? 63 : 15;
    const float* XG  = (l == 0) ? XG0 : XG1;
    u16* Hloc        = (l == 0) ? H0L : H1L;
    float cA = 0.f, cB = 0.f;

    for (int s = 0; s < T_STEPS; ++s) {
      const int slot = s & xmask;
      // fused poll: lanes 0-31 intra h flags (>= s), lanes 32-63 own xgate flag (>= s+1)
      {
        const unsigned* pp = (lane < 32) ? (intraF + (size_t)lane * 16)
                                         : (xflag + (size_t)slot * 32 + r);
        const unsigned need = (lane < 32) ? (unsigned)s : (unsigned)(s + 1);
        for (;;) {
          unsigned v = __hip_atomic_load(pp, __ATOMIC_RELAXED, __HIP_MEMORY_SCOPE_AGENT);
          if (__all((int)(v >= need))) break;
          __builtin_amdgcn_s_sleep(2);
        }
        asm volatile("" ::: "memory");
      }
      // x-gate loads (L3, overlap with h loads + MFMA; consumed in epilogue)
      const float* xb = XG + ((size_t)slot * 32 + r) * 4096 + (size_t)m2 * 128 + u;
      float xg[8];
      #pragma unroll
      for (int mt2 = 0; mt2 < 2; ++mt2)
        #pragma unroll
        for (int g = 0; g < 4; ++g)
          xg[mt2 * 4 + g] = __hip_atomic_load(xb + mt2 * 2048 + g * 32,
                                              __ATOMIC_RELAXED, __HIP_MEMORY_SCOPE_AGENT);
      // h loads from own-XCD L2 (sc0)
      const u16* hb0 = Hloc + (size_t)(s & 7) * BH + (size_t)l15 * 1024 + ks * 256 + lq * 8;
      const u16* hb1 = hb0 + 16 * 1024;
      f32x4 A0,A1,A2,A3,A4,A5,A6,A7,A8,A9,A10,A11,A12,A13,A14,A15;
      LOAD16_SC0(hb0, hb1);
      __builtin_amdgcn_sched_barrier(0);
      AS_FROM_A();

      f32x4 acc0[4] = {{0,0,0,0},{0,0,0,0},{0,0,0,0},{0,0,0,0}};
      f32x4 acc1[4] = {{0,0,0,0},{0,0,0,0},{0,0,0,0},{0,0,0,0}};
      MFMA_ALL(AS);
      RED_WRITE();

      float gsum[2][4];
      RED_READ(gsum);
      #pragma unroll
      for (int mt2 = 0; mt2 < 2; ++mt2) {
        const int m = m2 + mt2 * 16;
        const float G0 = gsum[mt2][0] + xg[mt2 * 4 + 0];
        const float G1 = gsum[mt2][1] + xg[mt2 * 4 + 1];
        const float G2 = gsum[mt2][2] + xg[mt2 * 4 + 2];
        const float G3 = gsum[mt2][3] + xg[mt2 * 4 + 3];
        const float cold = (s == 0) ? c0in[(size_t)l * 32768 + (size_t)m * 1024 + col]
                                    : (mt2 ? cB : cA);
        const float cn = sigm(G1) * cold + sigm(G0) * tanhf(G2);
        const float hn = sigm(G3) * tanhf(cn);
        if (mt2) cB = cn; else cA = cn;
        const unsigned hb = f2bf(hn);
        st_u16_sc0(Hloc + (size_t)((s + 1) & 7) * BH + (size_t)m * 1024 + col, hb);
        if (l == 0)
          __hip_atomic_store(H0X + (size_t)(s + 1) * BH + (size_t)m * 1024 + col,
                             (u16)hb, __ATOMIC_RELAXED, __HIP_MEMORY_SCOPE_AGENT);
        else
          out[(size_t)s * BH + (size_t)m * 1024 + col] = hn;
        if (s == T_STEPS - 1) {
          out[MEM_ELEMS + (size_t)l * 32768 + (size_t)m * 1024 + col] = hn;
          out[MEM_ELEMS + 65536 + (size_t)l * 32768 + (size_t)m * 1024 + col] = cn;
        }
      }
      __syncthreads();   // drains all waves' stores; guards redf reuse
      if (tid == 0) {
        __hip_atomic_store(intraF + (size_t)r * 16, (unsigned)(s + 1),
                           __ATOMIC_RELAXED, __HIP_MEMORY_SCOPE_AGENT);
        if (l == 0) {
          __hip_atomic_store(&ctrl[CW_H0XF + r * 16], (unsigned)(s + 1),
                             __ATOMIC_RELAXED, __HIP_MEMORY_SCOPE_AGENT);
          if (r == 0)
            __hip_atomic_store(&ctrl[CW_L0P], (unsigned)(s + 1),
                               __ATOMIC_RELAXED, __HIP_MEMORY_SCOPE_AGENT);
        } else if (r == 0) {
          __hip_atomic_store(&ctrl[CW_L1P], (unsigned)(s + 1),
                             __ATOMIC_RELAXED, __HIP_MEMORY_SCOPE_AGENT);
        }
      }
    }
    return;
  }

  // ================= XG0 workers (X @ W_ih0^T + bias0), XCDs 2-4 =================
  if (kind == 2u) {
    unsigned* cnt = ctrl + CW_CNT0 + r;
    for (;;) {
      if (tid == 0) {
        unsigned t = __hip_atomic_fetch_add(cnt, 1u, __ATOMIC_RELAXED, __HIP_MEMORY_SCOPE_AGENT);
        redf[0][0][0][0] = __builtin_bit_cast(float, t);
      }
      __syncthreads();
      const unsigned s = __builtin_bit_cast(unsigned, redf[0][0][0][0]);
      __syncthreads();
      if (s >= (unsigned)T_STEPS) break;
      if (s >= 60u)
        while (__hip_atomic_load(&ctrl[CW_L0P], __ATOMIC_RELAXED, __HIP_MEMORY_SCOPE_AGENT)
               < s - 56u) __builtin_amdgcn_s_sleep(8);

      const float* xs = X + (size_t)s * BH;
      short8 AS[16];
      #pragma unroll
      for (int kc = 0; kc < 8; ++kc) {
        const float* p0 = xs + (size_t)l15 * 1024 + ks * 256 + kc * 32 + lq * 8;
        const float* p1 = p0 + 16 * 1024;
        float4 a = *(const float4*)p0, b = *(const float4*)(p0 + 4);
        float4 c = *(const float4*)p1, d = *(const float4*)(p1 + 4);
        short8 s0, s1;
        s0[0]=(short)f2bf(a.x); s0[1]=(short)f2bf(a.y); s0[2]=(short)f2bf(a.z); s0[3]=(short)f2bf(a.w);
        s0[4]=(short)f2bf(b.x); s0[5]=(short)f2bf(b.y); s0[6]=(short)f2bf(b.z); s0[7]=(short)f2bf(b.w);
        s1[0]=(short)f2bf(c.x); s1[1]=(short)f2bf(c.y); s1[2]=(short)f2bf(c.z); s1[3]=(short)f2bf(c.w);
        s1[4]=(short)f2bf(d.x); s1[5]=(short)f2bf(d.y); s1[6]=(short)f2bf(d.z); s1[7]=(short)f2bf(d.w);
        AS[kc] = s0; AS[8 + kc] = s1;
      }
      f32x4 acc0[4] = {{0,0,0,0},{0,0,0,0},{0,0,0,0},{0,0,0,0}};
      f32x4 acc1[4] = {{0,0,0,0},{0,0,0,0},{0,0,0,0},{0,0,0,0}};
      MFMA_ALL(AS);
      RED_WRITE();
      float gsum[2][4];
      RED_READ(gsum);
      float* xgp = XG0 + ((size_t)(s & 63u) * 32 + r) * 4096;
      #pragma unroll
      for (int mt2 = 0; mt2 < 2; ++mt2)
        #pragma unroll
        for (int g = 0; g < 4; ++g)
          __hip_atomic_store(xgp + (size_t)(m2 + mt2 * 16) * 128 + g * 32 + u,
                             gsum[mt2][g] + bs[g],
                             __ATOMIC_RELAXED, __HIP_MEMORY_SCOPE_AGENT);
      __syncthreads();
      if (tid == 0)
        __hip_atomic_store(&ctrl[CW_XF0 + (s & 63u) * 32 + r], s + 1u,
                           __ATOMIC_RELAXED, __HIP_MEMORY_SCOPE_AGENT);
    }
    return;
  }

  // ================= XG1 workers (h0_out @ W_ih1^T + bias1), XCDs 5-7 =================
  {
    unsigned* cnt = ctrl + CW_CNT1 + r;
    for (;;) {
      if (tid == 0) {
        unsigned t = __hip_atomic_fetch_add(cnt, 1u, __ATOMIC_RELAXED, __HIP_MEMORY_SCOPE_AGENT);
        redf[0][0][0][0] = __builtin_bit_cast(float, t);
      }
      __syncthreads();
      const unsigned s = __builtin_bit_cast(unsigned, redf[0][0][0][0]);
      __syncthreads();
      if (s >= (unsigned)T_STEPS) break;
      // gate: full h0@(s+1) published by all 32 l0 blocks
      {
        const unsigned* p = ctrl + CW_H0XF + (size_t)(lane & 31) * 16;
        for (;;) {
          unsigned v = __hip_atomic_load(p, __ATOMIC_RELAXED, __HIP_MEMORY_SCOPE_AGENT);
          if (__all((int)(v >= s + 1u))) break;
          __builtin_amdgcn_s_sleep(4);
        }
        asm volatile("" ::: "memory");
      }
      if (s >= 13u)
        while (__hip_atomic_load(&ctrl[CW_L1P], __ATOMIC_RELAXED, __HIP_MEMORY_SCOPE_AGENT)
               < s - 12u) __builtin_amdgcn_s_sleep(8);

      const u16* hb0 = H0X + (size_t)(s + 1) * BH + (size_t)l15 * 1024 + ks * 256 + lq * 8;
      const u16* hb1 = hb0 + 16 * 1024;
      short8 AS[16];
      #pragma unroll
      for (int kc = 0; kc < 8; ++kc) {
        AS[kc]     = ld_sc16(hb0 + kc * 32);
        AS[8 + kc] = ld_sc16(hb1 + kc * 32);
      }
      f32x4 acc0[4] = {{0,0,0,0},{0,0,0,0},{0,0,0,0},{0,0,0,0}};
      f32x4 acc1[4] = {{0,0,0,0},{0,0,0,0},{0,0,0,0},{0,0,0,0}};
      MFMA_ALL(AS);
      RED_WRITE();
      float gsum[2][4];
      RED_READ(gsum);
      float* xgp = XG1 + ((size_t)(s & 15u) * 32 + r) * 4096;
      #pragma unroll
      for (int mt2 = 0; mt2 < 2; ++mt2)
        #pragma unroll
        for (int g = 0; g < 4; ++g)
          __hip_atomic_store(xgp + (size_t)(m2 + mt2 * 16) * 128 + g * 32 + u,
                             gsum[mt2][g] + bs[g],
                             __ATOMIC_RELAXED, __HIP_MEMORY_SCOPE_AGENT);
      __syncthreads();
      if (tid == 0)
        __hip_atomic_store(&ctrl[CW_XF1 + (s & 15u) * 32 + r], s + 1u,
                           __ATOMIC_RELAXED, __HIP_MEMORY_SCOPE_AGENT);
    }
  }
#undef MFMA_ALL
#undef RED_WRITE
#undef RED_READ
#undef LOAD16_SC0
#undef AS_FROM_A
}

// ---------------- tier-2: per-step launches (round-1 proven) ----------------
__global__ void cvt_t2(const float* __restrict__ Wih, const float* __restrict__ Whh,
                       const float* __restrict__ bih, const float* __restrict__ bhh,
                       const float* __restrict__ h0,
                       u16* __restrict__ Wcat, float* __restrict__ bias,
                       u16* __restrict__ h0pp, u16* __restrict__ h1pp) {
  size_t idx = (size_t)blockIdx.x * blockDim.x + threadIdx.x;
  size_t stride = (size_t)gridDim.x * blockDim.x;
  const size_t NW = (size_t)2 * G4H * 2048;
  for (size_t i = idx; i < NW; i += stride) {
    size_t ln = i >> 11;
    int k = (int)(i & 2047);
    float v = (k < HID) ? Wih[ln * HID + k] : Whh[ln * HID + (k - HID)];
    Wcat[i] = f2bf(v);
  }
  for (size_t i = idx; i < (size_t)2 * G4H; i += stride) bias[i] = bih[i] + bhh[i];
  for (size_t i = idx; i < (size_t)2 * BH; i += stride) {
    unsigned short v = f2bf(h0[i]);
    if (i < (size_t)BH) h0pp[(size_t)BH + i] = v;
    else                h1pp[(size_t)BH + (i - BH)] = v;
  }
}

__global__ __launch_bounds__(256) void lstm_step(
    const float* __restrict__ input, const u16* __restrict__ Wcat,
    const float* __restrict__ bias, u16* __restrict__ h0pp, u16* __restrict__ h1pp,
    const float* __restrict__ c0, float* __restrict__ out, int t)
{
  const bool is_l1 = (blockIdx.x >= 128);
  const int s = is_l1 ? (t - 1) : t;
  if (s < 0 || s >= T_STEPS) return;
  const int l = is_l1 ? 1 : 0;
  const int cb = blockIdx.x & 127;
  const int j0 = cb << 3;
  const int tid = threadIdx.x;
  const int lane = tid & 63;
  const int wid = tid >> 6;
  const int l15 = lane & 15;
  const int lq  = lane >> 4;
  const int koff = lq << 3;
  const int k0 = wid << 9;

  const int row0 = (l15 < 8) ? (j0 + l15) : (HID + j0 + l15 - 8);
  const int row1 = (l15 < 8) ? (2 * HID + j0 + l15) : (3 * HID + j0 + l15 - 8);
  const u16* bp0 = Wcat + ((size_t)l * G4H + row0) * 2048 + k0 + koff;
  const u16* bp1 = Wcat + ((size_t)l * G4H + row1) * 2048 + k0 + koff;

  f32x4 acc00 = {0.f, 0.f, 0.f, 0.f};
  f32x4 acc01 = acc00, acc10 = acc00, acc11 = acc00;

  const bool a_f32 = (!is_l1) && (wid < 2);
  if (a_f32) {
    const float* base = input + (size_t)s * BH + k0 + koff;
    const float* af0 = base + (size_t)l15 * HID;
    const float* af1 = base + (size_t)(16 + l15) * HID;
    #pragma unroll 4
    for (int kss = 0; kss < 16; ++kss) {
      const int kk = kss * 32;
      short8 b0 = *(const short8*)(bp0 + kk);
      short8 b1 = *(const short8*)(bp1 + kk);
      float4 q0 = *(const float4*)(af0 + kk);
      float4 q1 = *(const float4*)(af0 + kk + 4);
      float4 y0 = *(const float4*)(af1 + kk);
      float4 y1 = *(const float4*)(af1 + kk + 4);
      short8 a0, a1;
      a0[0]=(short)f2bf(q0.x); a0[1]=(short)f2bf(q0.y); a0[2]=(short)f2bf(q0.z); a0[3]=(short)f2bf(q0.w);
      a0[4]=(short)f2bf(q1.x); a0[5]=(short)f2bf(q1.y); a0[6]=(short)f2bf(q1.z); a0[7]=(short)f2bf(q1.w);
      a1[0]=(short)f2bf(y0.x); a1[1]=(short)f2bf(y0.y); a1[2]=(short)f2bf(y0.z); a1[3]=(short)f2bf(y0.w);
      a1[4]=(short)f2bf(y1.x); a1[5]=(short)f2bf(y1.y); a1[6]=(short)f2bf(y1.z); a1[7]=(short)f2bf(y1.w);
      acc00 = __builtin_amdgcn_mfma_f32_16x16x32_bf16(a0, b0, acc00, 0, 0, 0);
      acc01 = __builtin_amdgcn_mfma_f32_16x16x32_bf16(a0, b1, acc01, 0, 0, 0);
      acc10 = __builtin_amdgcn_mfma_f32_16x16x32_bf16(a1, b0, acc10, 0, 0, 0);
      acc11 = __builtin_amdgcn_mfma_f32_16x16x32_bf16(a1, b1, acc11, 0, 0, 0);
    }
  } else {
    const u16* src; int ksrc;
    if (!is_l1)       { src = h0pp + (size_t)(((s + 1) & 1)) * BH; ksrc = k0 - HID; }
    else if (wid < 2) { src = h0pp + (size_t)((s & 1)) * BH;       ksrc = k0;       }
    else              { src = h1pp + (size_t)(((s + 1) & 1)) * BH; ksrc = k0 - HID; }
    const u16* ab0 = src + (size_t)l15 * HID + ksrc + koff;
    const u16* ab1 = src + (size_t)(16 + l15) * HID + ksrc + koff;
    #pragma unroll 4
    for (int kss = 0; kss < 16; ++kss) {
      const int kk = kss * 32;
      short8 b0 = *(const short8*)(bp0 + kk);
      short8 b1 = *(const short8*)(bp1 + kk);
      short8 a0 = *(const short8*)(ab0 + kk);
      short8 a1 = *(const short8*)(ab1 + kk);
      acc00 = __builtin_amdgcn_mfma_f32_16x16x32_bf16(a0, b0, acc00, 0, 0, 0);
      acc01 = __builtin_amdgcn_mfma_f32_16x16x32_bf16(a0, b1, acc01, 0, 0, 0);
      acc10 = __builtin_amdgcn_mfma_f32_16x16x32_bf16(a1, b0, acc10, 0, 0, 0);
      acc11 = __builtin_amdgcn_mfma_f32_16x16x32_bf16(a1, b1, acc11, 0, 0, 0);
    }
  }

  __shared__ float red[4][2][2][256];
  #pragma unroll
  for (int q = 0; q < 4; ++q) {
    red[wid][0][0][lane * 4 + q] = acc00[q];
    red[wid][0][1][lane * 4 + q] = acc01[q];
    red[wid][1][0][lane * 4 + q] = acc10[q];
    red[wid][1][1][lane * 4 + q] = acc11[q];
  }
  __syncthreads();

  const int m  = tid >> 3;
  const int jj = tid & 7;
  const int j  = j0 + jj;
  const int mt = m >> 4;
  const int mm = m & 15;
  const int rr = mm & 3;
  const int lbase = (mm >> 2) << 4;

  float g4[4];
  #pragma unroll
  for (int gate = 0; gate < 4; ++gate) {
    const int nt = gate >> 1;
    const int nn = ((gate & 1) << 3) + jj;
    const int li = (lbase | nn) * 4 + rr;
    float v = red[0][mt][nt][li] + red[1][mt][nt][li] +
              red[2][mt][nt][li] + red[3][mt][nt][li];
    g4[gate] = v + bias[l * G4H + gate * HID + j];
  }

  float* hT     = out + MEM_ELEMS;
  float* cstate = out + MEM_ELEMS + 2 * (size_t)BH;
  const size_t cidx = (size_t)l * BH + (size_t)m * HID + j;
  const float c_old = (s == 0) ? c0[cidx] : cstate[cidx];
  const float c_new = sigm(g4[1]) * c_old + sigm(g4[0]) * tanhf(g4[2]);
  const float h_new = sigm(g4[3]) * tanhf(c_new);
  cstate[cidx] = c_new;
  u16* ppw = (is_l1 ? h1pp : h0pp) + (size_t)(s & 1) * BH;
  ppw[m * HID + j] = f2bf(h_new);
  if (is_l1) out[(size_t)s * BH + (size_t)m * HID + j] = h_new;
  if (s == T_STEPS - 1) hT[cidx] = h_new;
}

// ---------------- tier-3: fp32 fallback ----------------
__global__ void fb_init(const float* __restrict__ h0, float* __restrict__ h0ppf,
                        float* __restrict__ h1ppf) {
  int i = blockIdx.x * blockDim.x + threadIdx.x;
  if (i < BH) h0ppf[BH + i] = h0[i];
  else if (i < 2 * BH) h1ppf[BH + (i - BH)] = h0[i];
}

__global__ __launch_bounds__(256) void fb_step(
    const float* __restrict__ input, const float* __restrict__ Wih,
    const float* __restrict__ Whh, const float* __restrict__ bih,
    const float* __restrict__ bhh, float* __restrict__ h0ppf, float* __restrict__ h1ppf,
    const float* __restrict__ c0, float* __restrict__ out, int t)
{
  const bool is_l1 = (blockIdx.x >= 128);
  const int s = is_l1 ? (t - 1) : t;
  if (s < 0 || s >= T_STEPS) return;
  const int l = is_l1 ? 1 : 0;
  const int cb = blockIdx.x & 127, j0 = cb << 3, tid = threadIdx.x;
  const float* xsrc = is_l1 ? (h0ppf + (size_t)(s & 1) * BH) : (input + (size_t)s * BH);
  const float* hsrc = (is_l1 ? h1ppf : h0ppf) + (size_t)((s + 1) & 1) * BH;
  const int c = tid & 31, mg = tid >> 5;
  const int gate = c >> 3, jc = c & 7;
  const int row = gate * HID + j0 + jc;
  const float* wi = Wih + ((size_t)l * G4H + row) * HID;
  const float* wh = Whh + ((size_t)l * G4H + row) * HID;
  float a0 = 0, a1 = 0, a2 = 0, a3 = 0;
  const float* x0 = xsrc + (size_t)(mg * 4 + 0) * HID;
  const float* x1 = xsrc + (size_t)(mg * 4 + 1) * HID;
  const float* x2 = xsrc + (size_t)(mg * 4 + 2) * HID;
  const float* x3 = xsrc + (size_t)(mg * 4 + 3) * HID;
  const float* h0p = hsrc + (size_t)(mg * 4 + 0) * HID;
  const float* h1p = hsrc + (size_t)(mg * 4 + 1) * HID;
  const float* h2p = hsrc + (size_t)(mg * 4 + 2) * HID;
  const float* h3p = hsrc + (size_t)(mg * 4 + 3) * HID;
  for (int k = 0; k < HID; ++k) {
    float wa = wi[k], wb2 = wh[k];
    a0 += x0[k] * wa + h0p[k] * wb2;
    a1 += x1[k] * wa + h1p[k] * wb2;
    a2 += x2[k] * wa + h2p[k] * wb2;
    a3 += x3[k] * wa + h3p[k] * wb2;
  }
  __shared__ float gl[32][32];
  const float bsum = bih[l * G4H + row] + bhh[l * G4H + row];
  gl[mg * 4 + 0][c] = a0 + bsum;
  gl[mg * 4 + 1][c] = a1 + bsum;
  gl[mg * 4 + 2][c] = a2 + bsum;
  gl[mg * 4 + 3][c] = a3 + bsum;
  __syncthreads();
  const int m = tid >> 3, jj = tid & 7, j = j0 + jj;
  float g4[4];
  #pragma unroll
  for (int g = 0; g < 4; ++g) g4[g] = gl[m][g * 8 + jj];
  float* hT = out + MEM_ELEMS;
  float* cstate = out + MEM_ELEMS + 2 * (size_t)BH;
  const size_t cidx = (size_t)l * BH + (size_t)m * HID + j;
  const float c_old = (s == 0) ? c0[cidx] : cstate[cidx];
  const float c_new = sigm(g4[1]) * c_old + sigm(g4[0]) * tanhf(g4[2]);
  const float h_new = sigm(g4[3]) * tanhf(c_new);
  cstate[cidx] = c_new;
  float* ppw = (is_l1 ? h1ppf : h0ppf) + (size_t)(s & 1) * BH;
  ppw[m * HID + j] = h_new;
  if (is_l1) out[(size_t)s * BH + (size_t)m * HID + j] = h_new;
  if (s == T_STEPS - 1) hT[cidx] = h_new;
}

extern "C" void kernel_launch(void* const* d_in, const int* in_sizes, int n_in,
                              void* d_out, int out_size, void* d_ws, size_t ws_size,
                              hipStream_t stream) {
  const float* input = (const float*)d_in[0];
  const float* h0    = (const float*)d_in[1];
  const float* c0    = (const float*)d_in[2];
  const float* Wih   = (const float*)d_in[3];
  const float* Whh   = (const float*)d_in[4];
  const float* bih   = (const float*)d_in[5];
  const float* bhh   = (const float*)d_in[6];
  float* out = (float*)d_out;
  char* ws = (char*)d_ws;

  if (ws_size >= WS_MESH) {
    int occ = 0;   // must be exactly 1 block/CU for the XCD role claim
    (void)hipOccupancyMaxActiveBlocksPerMultiprocessor(&occ, lstm_mesh, 512, 0);
    if (occ == 1) {
      u16*   WFHH = (u16*)(ws + OFF_WFHH);
      u16*   WFI0 = (u16*)(ws + OFF_WFI0);
      u16*   WFI1 = (u16*)(ws + OFF_WFI1);
      float* bias = (float*)(ws + OFF_BIAS);
      u16*   H0L  = (u16*)(ws + OFF_H0L);
      u16*   H1L  = (u16*)(ws + OFF_H1L);
      u16*   H0X  = (u16*)(ws + OFF_H0X);
      float* XG0  = (float*)(ws + OFF_XG0);
      float* XG1  = (float*)(ws + OFF_XG1);
      unsigned* ctrl = (unsigned*)(ws + OFF_CTRL);
      hipMemsetAsync(ws + OFF_CTRL, 0, 65536, stream);
      cvt_mesh<<<2048, 256, 0, stream>>>(Wih, Whh, bih, bhh, h0,
                                         WFHH, WFI0, WFI1, bias, H0L, H1L);
      lstm_mesh<<<256, 512, 0, stream>>>(input, c0, out, WFHH, WFI0, WFI1, bias,
                                         H0L, H1L, H0X, XG0, XG1, ctrl);
      return;
    }
  }
  if (ws_size >= WS_STEP) {
    u16*   Wcat = (u16*)(ws + T2_W);
    float* bias = (float*)(ws + T2_BIAS);
    u16*   h0pp = (u16*)(ws + T2_H0);
    u16*   h1pp = (u16*)(ws + T2_H1);
    cvt_t2<<<4096, 256, 0, stream>>>(Wih, Whh, bih, bhh, h0, Wcat, bias, h0pp, h1pp);
    for (int t = 0; t <= T_STEPS; ++t)
      lstm_step<<<256, 256, 0, stream>>>(input, Wcat, bias, h0pp, h1pp, c0, out, t);
  } else {
    float* h0ppf = (float*)ws;
    float* h1ppf = (float*)(ws + (size_t)2 * BH * 4);
    fb_init<<<256, 256, 0, stream>>>(h0, h0ppf, h1ppf);
    for (int t = 0; t <= T_STEPS; ++t)
      fb_step<<<256, 256, 0, stream>>>(input, Wih, Whh, bih, bhh, h0ppf, h1ppf, c0, out, t);
  }
}